// Round 4
// baseline (244.709 us; speedup 1.0000x reference)
//
#include <hip/hip_runtime.h>

#define BLOCK 256

typedef float v2f __attribute__((ext_vector_type(2)));

enum LId {FU1,FU2,KU1,KU2,HU1,HU2,MD1,MD2,MD3,HD1,HD2,KD1,KD2,HA1,HA2,KA1,KA2,FA1,FA2};

// din*dout per layer; dup-buffer layout: per layer, weights then bias, each
// element stored twice ({v,v}) so a uniform 8B load gives an SGPR pair.
__constant__ const int WN[19] = {4,4,16,16,36,36,176,256,96,24,16,8,4,32,4,24,4,16,4};
__constant__ const int BN[19] = {2,2, 4, 4, 6, 6, 16, 16, 6, 4, 4,2,2, 4,1, 4,1, 4,1};
// v2f-offsets (prefix sums), hardcoded:
__constant__ const int WOFF[19] = {0,6,12,32,52,94,136,328,600,702,730,750,760,766,802,807,835,840,860};
__constant__ const int BOFF[19] = {4,10,28,48,88,130,312,584,696,726,746,758,764,798,806,831,839,856,864};
// total 865 v2f = 1730 floats

struct PrepArgs {
    const float* w[19];
    const float* b[19];
};

__global__ __launch_bounds__(256) void prep_kernel(PrepArgs P, float* __restrict__ ws) {
    const int tid = threadIdx.x;
    for (int L = 0; L < 19; ++L) {
        const float* w = P.w[L];
        for (int e = tid; e < WN[L]; e += 256) {
            float v = w[e];
            ws[2*(WOFF[L]+e)+0] = v;
            ws[2*(WOFF[L]+e)+1] = v;
        }
        const float* b = P.b[L];
        for (int e = tid; e < BN[L]; e += 256) {
            float v = b[e];
            ws[2*(BOFF[L]+e)+0] = v;
            ws[2*(BOFF[L]+e)+1] = v;
        }
    }
}

// Each v2f activation holds one feature for 2 adjacent rows.
// w2/b2 are wave-uniform addresses into the dup buffer -> s_load_dwordx2 ->
// SGPR pair -> v_pk_fma_f32 acc, in, s[pair] : 2 FMAs per instruction.
template<int DIN,int DOUT,bool RELU>
__device__ __forceinline__ void lin(const v2f (&in)[DIN], v2f (&out)[DOUT],
                                    const v2f* __restrict__ w2, const v2f* __restrict__ b2) {
#pragma unroll
    for (int j = 0; j < DOUT; ++j) {
        v2f acc = b2[j];
#pragma unroll
        for (int i = 0; i < DIN; ++i)
            acc = __builtin_elementwise_fma(in[i], w2[i*DOUT + j], acc);
        if (RELU) {
            v2f z = {0.0f, 0.0f};
            out[j] = __builtin_elementwise_max(acc, z);
        } else {
            out[j] = acc;
        }
    }
}

__global__ __launch_bounds__(BLOCK, 4) void pnet_kernel(
    const float* __restrict__ x, float* __restrict__ out, int B,
    const float* __restrict__ ws) {
    const long long t = (long long)blockIdx.x * BLOCK + threadIdx.x;
    const long long row0 = t * 2;
    if (row0 >= B) return;
    const bool full = (row0 + 2) <= B;

    const v2f* dup = (const v2f*)ws;

    // ---- load 2 rows x 11 features; transpose to per-feature pairs ----
    v2f xin[11];
    if (full) {
        const v2f* p = (const v2f*)(x + row0 * 11);  // 88*t bytes, 8B aligned
        v2f v[11];
#pragma unroll
        for (int i = 0; i < 11; ++i) v[i] = p[i];
        const float* fv = (const float*)&v[0];
#pragma unroll
        for (int c = 0; c < 11; ++c) { xin[c].x = fv[c]; xin[c].y = fv[11 + c]; }
    } else {
        const float* pr = x + row0 * 11;
#pragma unroll
        for (int c = 0; c < 11; ++c) { xin[c].x = pr[c]; xin[c].y = pr[c]; }
    }

    // ---- f_up: [f, fd] -> 2 -> 2 ----
    v2f fin[2] = {xin[4], xin[10]};
    v2f tf[2], f_up[2];
    lin<2,2,true>(fin, tf, dup+WOFF[FU1], dup+BOFF[FU1]);
    lin<2,2,true>(tf, f_up, dup+WOFF[FU2], dup+BOFF[FU2]);

    // ---- k_up: [k, kd, f_up] -> 4 -> 4 ----
    v2f kin[4] = {xin[3], xin[9], f_up[0], f_up[1]};
    v2f tk[4], k_up[4];
    lin<4,4,true>(kin, tk, dup+WOFF[KU1], dup+BOFF[KU1]);
    lin<4,4,true>(tk, k_up, dup+WOFF[KU2], dup+BOFF[KU2]);

    // ---- h_up: [h, hd, k_up] -> 6 -> 6 ----
    v2f hin[6] = {xin[2], xin[8], k_up[0], k_up[1], k_up[2], k_up[3]};
    v2f th[6], h_up[6];
    lin<6,6,true>(hin, th, dup+WOFF[HU1], dup+BOFF[HU1]);
    lin<6,6,true>(th, h_up, dup+WOFF[HU2], dup+BOFF[HU2]);

    // ---- m_down: [m_obs(5), h_up(6)] -> 16 -> 16 -> 6 ----
    v2f min_[11] = {xin[0], xin[1], xin[5], xin[6], xin[7],
                    h_up[0], h_up[1], h_up[2], h_up[3], h_up[4], h_up[5]};
    v2f t16a[16], t16b[16], m_down[6];
    lin<11,16,true>(min_, t16a, dup+WOFF[MD1], dup+BOFF[MD1]);
    lin<16,16,true>(t16a, t16b, dup+WOFF[MD2], dup+BOFF[MD2]);
    lin<16,6,true>(t16b, m_down, dup+WOFF[MD3], dup+BOFF[MD3]);

    // ---- h_down: m_down -> 4 -> 4 ----
    v2f t4b[4], h_down[4];
    lin<6,4,true>(m_down, t4b, dup+WOFF[HD1], dup+BOFF[HD1]);
    lin<4,4,true>(t4b, h_down, dup+WOFF[HD2], dup+BOFF[HD2]);

    // ---- k_down: h_down -> 2 -> 2 ----
    v2f t2b[2], k_down[2];
    lin<4,2,true>(h_down, t2b, dup+WOFF[KD1], dup+BOFF[KD1]);
    lin<2,2,true>(t2b, k_down, dup+WOFF[KD2], dup+BOFF[KD2]);

    // ---- h_act: [h, hd, m_down(6)] -> 4 -> 1 (no relu on last) ----
    v2f ha_in[8] = {xin[2], xin[8], m_down[0], m_down[1], m_down[2], m_down[3], m_down[4], m_down[5]};
    v2f t4c[4], h_act[1];
    lin<8,4,true>(ha_in, t4c, dup+WOFF[HA1], dup+BOFF[HA1]);
    lin<4,1,false>(t4c, h_act, dup+WOFF[HA2], dup+BOFF[HA2]);

    // ---- k_act: [k, kd, h_down(4)] -> 4 -> 1 ----
    v2f ka_in[6] = {xin[3], xin[9], h_down[0], h_down[1], h_down[2], h_down[3]};
    v2f t4d[4], k_act[1];
    lin<6,4,true>(ka_in, t4d, dup+WOFF[KA1], dup+BOFF[KA1]);
    lin<4,1,false>(t4d, k_act, dup+WOFF[KA2], dup+BOFF[KA2]);

    // ---- f_act: [f, fd, k_down(2)] -> 4 -> 1 ----
    v2f fa_in[4] = {xin[4], xin[10], k_down[0], k_down[1]};
    v2f t4e[4], f_act[1];
    lin<4,4,true>(fa_in, t4e, dup+WOFF[FA1], dup+BOFF[FA1]);
    lin<4,1,false>(t4e, f_act, dup+WOFF[FA2], dup+BOFF[FA2]);

    // ---- store: per row [h_act, f_act, k_act] ----
    if (full) {
        float ob[6] = {h_act[0].x, f_act[0].x, k_act[0].x,
                       h_act[0].y, f_act[0].y, k_act[0].y};
        v2f* po = (v2f*)(out + row0 * 3);  // 24*row0 bytes, 8B aligned
#pragma unroll
        for (int i = 0; i < 3; ++i) po[i] = ((const v2f*)ob)[i];
    } else {
        out[row0*3+0] = h_act[0].x;
        out[row0*3+1] = f_act[0].x;
        out[row0*3+2] = k_act[0].x;
    }
}

extern "C" void kernel_launch(void* const* d_in, const int* in_sizes, int n_in,
                              void* d_out, int out_size, void* d_ws, size_t ws_size,
                              hipStream_t stream) {
    const float* x = (const float*)d_in[0];
    float* out = (float*)d_out;
    const int B = in_sizes[0] / 11;

    PrepArgs P;
    for (int i = 0; i < 19; ++i) {
        P.w[i] = (const float*)d_in[1 + 2*i];
        P.b[i] = (const float*)d_in[2 + 2*i];
    }

    // duplicate weights/biases into d_ws as {v,v} pairs (1730 floats)
    prep_kernel<<<1, 256, 0, stream>>>(P, (float*)d_ws);

    const long long nthreads = ((long long)B + 1) / 2;
    const int blocks = (int)((nthreads + BLOCK - 1) / BLOCK);
    pnet_kernel<<<blocks, BLOCK, 0, stream>>>(x, out, B, (const float*)d_ws);
}

// Round 5
// 236.363 us; speedup vs baseline: 1.0353x; 1.0353x over previous
//
#include <hip/hip_runtime.h>

#define BLOCK 256

struct WPtrs {
    const float* w[19];
    const float* b[19];
};

enum LId {FU1,FU2,KU1,KU2,HU1,HU2,MD1,MD2,MD3,HD1,HD2,KD1,KD2,HA1,HA2,KA1,KA2,FA1,FA2};

// One row per thread, scalar math. Weight is wave-uniform -> SGPR operand of
// v_fmac_f32: exactly 1 VALU inst per weight. Live set (~50 floats) fits the
// 64-VGPR / 8-waves-per-SIMD budget -> no scratch spills (the R3/R4 stall).
template<int DIN,int DOUT,bool RELU>
__device__ __forceinline__ void lin(const float (&in)[DIN], float (&out)[DOUT],
                                    const float* __restrict__ w, const float* __restrict__ b) {
#pragma unroll
    for (int j = 0; j < DOUT; ++j) {
        float acc = b[j];
#pragma unroll
        for (int i = 0; i < DIN; ++i)
            acc = __builtin_fmaf(in[i], w[i*DOUT + j], acc);
        out[j] = RELU ? fmaxf(acc, 0.0f) : acc;
    }
}

__global__ __launch_bounds__(BLOCK) void pnet_kernel(
    const float* __restrict__ x, float* __restrict__ out, int B, WPtrs P) {
    const long long row = (long long)blockIdx.x * BLOCK + threadIdx.x;
    if (row >= B) return;

    // ---- load 11 features (coalesced within wave; 44B/thread) ----
    float xin[11];
    const float* pr = x + row * 11;
#pragma unroll
    for (int c = 0; c < 11; ++c) xin[c] = pr[c];

    // ---- f_up: [f, fd] -> 2 -> 2 ----
    float fin[2] = {xin[4], xin[10]};
    float tf[2], f_up[2];
    lin<2,2,true>(fin, tf, P.w[FU1], P.b[FU1]);
    lin<2,2,true>(tf, f_up, P.w[FU2], P.b[FU2]);

    // ---- k_up: [k, kd, f_up] -> 4 -> 4 ----
    float kin[4] = {xin[3], xin[9], f_up[0], f_up[1]};
    float tk[4], k_up[4];
    lin<4,4,true>(kin, tk, P.w[KU1], P.b[KU1]);
    lin<4,4,true>(tk, k_up, P.w[KU2], P.b[KU2]);

    // ---- h_up: [h, hd, k_up] -> 6 -> 6 ----
    float hin[6] = {xin[2], xin[8], k_up[0], k_up[1], k_up[2], k_up[3]};
    float th[6], h_up[6];
    lin<6,6,true>(hin, th, P.w[HU1], P.b[HU1]);
    lin<6,6,true>(th, h_up, P.w[HU2], P.b[HU2]);

    // ---- m_down: [m_obs(5), h_up(6)] -> 16 -> 16 -> 6 ----
    float min_[11] = {xin[0], xin[1], xin[5], xin[6], xin[7],
                      h_up[0], h_up[1], h_up[2], h_up[3], h_up[4], h_up[5]};
    float t16a[16], t16b[16], m_down[6];
    lin<11,16,true>(min_, t16a, P.w[MD1], P.b[MD1]);
    lin<16,16,true>(t16a, t16b, P.w[MD2], P.b[MD2]);
    lin<16,6,true>(t16b, m_down, P.w[MD3], P.b[MD3]);

    // ---- h_down: m_down -> 4 -> 4 ----
    float t4b[4], h_down[4];
    lin<6,4,true>(m_down, t4b, P.w[HD1], P.b[HD1]);
    lin<4,4,true>(t4b, h_down, P.w[HD2], P.b[HD2]);

    // ---- k_down: h_down -> 2 -> 2 ----
    float t2b[2], k_down[2];
    lin<4,2,true>(h_down, t2b, P.w[KD1], P.b[KD1]);
    lin<2,2,true>(t2b, k_down, P.w[KD2], P.b[KD2]);

    // ---- h_act: [h, hd, m_down(6)] -> 4 -> 1 (no relu on last) ----
    float ha_in[8] = {xin[2], xin[8], m_down[0], m_down[1], m_down[2], m_down[3], m_down[4], m_down[5]};
    float t4c[4], h_act[1];
    lin<8,4,true>(ha_in, t4c, P.w[HA1], P.b[HA1]);
    lin<4,1,false>(t4c, h_act, P.w[HA2], P.b[HA2]);

    // ---- k_act: [k, kd, h_down(4)] -> 4 -> 1 ----
    float ka_in[6] = {xin[3], xin[9], h_down[0], h_down[1], h_down[2], h_down[3]};
    float t4d[4], k_act[1];
    lin<6,4,true>(ka_in, t4d, P.w[KA1], P.b[KA1]);
    lin<4,1,false>(t4d, k_act, P.w[KA2], P.b[KA2]);

    // ---- f_act: [f, fd, k_down(2)] -> 4 -> 1 ----
    float fa_in[4] = {xin[4], xin[10], k_down[0], k_down[1]};
    float t4e[4], f_act[1];
    lin<4,4,true>(fa_in, t4e, P.w[FA1], P.b[FA1]);
    lin<4,1,false>(t4e, f_act, P.w[FA2], P.b[FA2]);

    // ---- store: [h_act, f_act, k_act] (12B/thread, coalesced) ----
    float* po = out + row * 3;
    po[0] = h_act[0];
    po[1] = f_act[0];
    po[2] = k_act[0];
}

extern "C" void kernel_launch(void* const* d_in, const int* in_sizes, int n_in,
                              void* d_out, int out_size, void* d_ws, size_t ws_size,
                              hipStream_t stream) {
    const float* x = (const float*)d_in[0];
    float* out = (float*)d_out;
    const int B = in_sizes[0] / 11;

    WPtrs P;
    for (int i = 0; i < 19; ++i) {
        P.w[i] = (const float*)d_in[1 + 2*i];
        P.b[i] = (const float*)d_in[2 + 2*i];
    }

    const int blocks = (int)(((long long)B + BLOCK - 1) / BLOCK);
    pnet_kernel<<<blocks, BLOCK, 0, stream>>>(x, out, B, P);
}